// Round 3
// baseline (928.931 us; speedup 1.0000x reference)
//
#include <hip/hip_runtime.h>
#include <hip/hip_bf16.h>

#define DEV static __device__ __forceinline__

typedef short v8s __attribute__((ext_vector_type(8)));
typedef float v4f __attribute__((ext_vector_type(4)));
typedef unsigned short v4u __attribute__((ext_vector_type(4)));

constexpr int N_ = 8;
constexpr float EPS_ = 1e-5f;
constexpr float INV_CNT = 1.f / 524288.f;   // 1/(8*256*256)

// device-global scratch
__device__ __align__(16) unsigned short g_wT1[9*128*64];   // [tap][oc][ic] bf16
__device__ __align__(16) unsigned short g_wT2[9*64*128];
__device__ __align__(16) unsigned short g_whT[64*192];     // [oc][k] bf16
__device__ __align__(16) float g_stats[512];               // s1[0:256) s2[256:384) sH[384:512)
__device__ __align__(16) unsigned short g_zero[64];

DEV float bfbits2f(unsigned short u) { return __uint_as_float(((unsigned)u) << 16); }
DEV unsigned short f2bfbits(float f) {
    __hip_bfloat16 h = __float2bfloat16(f);
    unsigned short b;
    __builtin_memcpy(&b, &h, 2);
    return b;
}

DEV float mishf(float v) {
    // mish(v) = v * t(t+2)/(t(t+2)+2), t = e^v
    float t = __expf(fminf(v, 30.f));
    float num = fmaf(t, t, 2.f * t);
    return v * num * __builtin_amdgcn_rcpf(num + 2.f);
}

DEV void gll16(const unsigned short* g, unsigned short* l) {
    __builtin_amdgcn_global_load_lds(
        (const __attribute__((address_space(1))) unsigned int*)g,
        (__attribute__((address_space(3))) unsigned int*)l,
        16, 0, 0);
}

// ---------------------------------------------------------------------------
// prep: weight reorders (bf16) + zero stats + zero page
// ---------------------------------------------------------------------------
__global__ __launch_bounds__(256) void prep(const float* __restrict__ w1,
                                            const float* __restrict__ w2,
                                            const float* __restrict__ wh)
{
    int idx = blockIdx.x * 256 + threadIdx.x;
    if (idx < 512) g_stats[idx] = 0.f;
    if (idx < 64) g_zero[idx] = 0;
    if (idx < 12288) g_whT[idx] = f2bfbits(wh[idx]);       // [oc][192] == OIHW flat
    if (idx < 73728) {
        int tap = idx / 8192, rem = idx & 8191;
        {   int oc = rem >> 6, ic = rem & 63;
            g_wT1[idx] = f2bfbits(w1[(oc * 64 + ic) * 9 + tap]); }
        {   int oc = rem >> 7, ic = rem & 127;
            g_wT2[idx] = f2bfbits(w2[(oc * 128 + ic) * 9 + tap]); }
    }
}

// ---------------------------------------------------------------------------
// transpose x: NCHW f32 -> NHWC bf16
// ---------------------------------------------------------------------------
__global__ __launch_bounds__(256) void transpose_x(const float* __restrict__ x,
                                                   unsigned short* __restrict__ xh)
{
    __shared__ float t[64][65];
    const int tid = threadIdx.x;
    const int bid = blockIdx.x;
    const int n = bid >> 10, pb = bid & 1023;
    const size_t pix0 = (size_t)pb * 64;
    const float* xb = x + ((size_t)n << 22) + pix0;
#pragma unroll
    for (int cb = 0; cb < 4; ++cb) {
        int c = (tid >> 4) + cb * 16;
        int p = (tid & 15) * 4;
        float4 v = *(const float4*)(xb + ((size_t)c << 16) + p);
        t[c][p] = v.x; t[c][p+1] = v.y; t[c][p+2] = v.z; t[c][p+3] = v.w;
    }
    __syncthreads();
    unsigned short* ob = xh + (((size_t)n << 16) + pix0) * 64;
#pragma unroll
    for (int pb2 = 0; pb2 < 2; ++pb2) {
        int p = (tid >> 3) + pb2 * 32;
        int c0 = (tid & 7) * 8;
        v8s r;
#pragma unroll
        for (int i = 0; i < 8; ++i) r[i] = (short)f2bfbits(t[c0 + i][p]);
        *(v8s*)(ob + (size_t)p * 64 + c0) = r;
    }
}

// ---------------------------------------------------------------------------
// MFMA implicit-GEMM 3x3 conv, pad=1, NHWC bf16, fused per-channel stats.
// Block: 512 thr = 8 waves; block tile 64 oc x 128 pix; wave tile 32 oc x 32 pix.
// NH = IC_T/64 ic-halves staged sequentially per tile (weights reloaded per half).
// ---------------------------------------------------------------------------
template<int IC_T, int OC_T, int WSEL, int SOFF>
__global__ __launch_bounds__(512, 2) void convMFMA(const unsigned short* __restrict__ in,
                                                   unsigned short* __restrict__ outp,
                                                   const int nTiles)
{
    __shared__ __align__(16) unsigned short Xs[3 * 130 * 64];   // 49920 B (also C-tile, red)
    const unsigned short* wT = (WSEL == 0) ? g_wT1 : g_wT2;
    constexpr int NH = IC_T / 64;
    constexpr int NOCB = OC_T / 64;

    const int tid  = threadIdx.x;
    const int lane = tid & 63;
    const int wv   = tid >> 6;
    const int ocg = (NOCB == 2) ? ((int)blockIdx.x & 1) : 0;
    const int pg  = (NOCB == 2) ? ((int)blockIdx.x >> 1) : (int)blockIdx.x;
    const int NPG = (int)gridDim.x / NOCB;

    const int ocw = wv >> 2;
    const int wp  = (wv & 3) * 32;
    const int l15 = lane & 15, kg = lane >> 4;

    v8s av[9][2][2];
    auto loadW = [&](int icoff) {
        const unsigned short* wb =
            wT + ((size_t)(ocg * 64 + ocw * 32 + l15)) * IC_T + icoff + kg * 8;
#pragma unroll
        for (int tap = 0; tap < 9; ++tap)
#pragma unroll
            for (int ics = 0; ics < 2; ++ics)
#pragma unroll
                for (int sub = 0; sub < 2; ++sub)
                    av[tap][ics][sub] =
                        *(const v8s*)(wb + ((size_t)tap * OC_T + sub * 16) * IC_T + ics * 32);
    };
    if (NH == 1) loadW(0);

    float s8[8], q8[8];
#pragma unroll
    for (int j = 0; j < 8; ++j) { s8[j] = 0.f; q8[j] = 0.f; }

    for (int t = 0; t < nTiles; ++t) {
        const int pt   = pg + NPG * t;
        const int n    = pt >> 9;
        const int hrow = (pt >> 1) & 255;
        const int wblk = pt & 1;
        const int w0   = wblk * 128;
        const size_t pixbase = ((size_t)n << 16) + ((size_t)hrow << 8) + w0;

        v4f acc[2][2];
        {
            v4f z = {0.f, 0.f, 0.f, 0.f};
            acc[0][0] = z; acc[0][1] = z; acc[1][0] = z; acc[1][1] = z;
        }

#pragma unroll
        for (int h = 0; h < NH; ++h) {
            const int icoff = h * 64;
            __syncthreads();   // Xs free (prev reads done)
            {
                const int cb0 = wv * 64;
#pragma unroll
                for (int it = 0; it < 7; ++it) {
                    int cb = it * 512 + cb0;           // wave-uniform
                    int chunk = cb + lane;
                    if (chunk < 3120) {
                        int r   = chunk / 1040;
                        int rem = chunk - r * 1040;
                        int lc  = rem >> 3, k = rem & 7;
                        int gr  = hrow - 1 + r;
                        int gc  = w0 - 1 + lc;
                        const unsigned short* src;
                        if (((unsigned)gr < 256u) & ((unsigned)gc < 256u))
                            src = in + ((((size_t)n << 16) + ((size_t)gr << 8) + gc) * IC_T)
                                     + icoff + ((k ^ (lc & 7)) << 3);
                        else
                            src = g_zero;
                        gll16(src, Xs + (size_t)cb * 8);
                    }
                }
            }
            if (NH > 1) loadW(icoff);
            __syncthreads();   // drains vmcnt

#pragma unroll
            for (int tap = 0; tap < 9; ++tap) {
                const int dyy = tap / 3, dxx = tap % 3;
                const int lc0 = wp + l15 + dxx;
#pragma unroll
                for (int ics = 0; ics < 2; ++ics) {
                    const int off0 = ((dyy * 130 + lc0) * 8 + ((ics * 4 + kg) ^ (lc0 & 7))) * 8;
                    v8s b0 = *(const v8s*)(Xs + off0);
                    v8s b1 = *(const v8s*)(Xs + off0 + 16 * 64);
                    acc[0][0] = __builtin_amdgcn_mfma_f32_16x16x32_bf16(av[tap][ics][0], b0, acc[0][0], 0, 0, 0);
                    acc[1][0] = __builtin_amdgcn_mfma_f32_16x16x32_bf16(av[tap][ics][1], b0, acc[1][0], 0, 0, 0);
                    acc[0][1] = __builtin_amdgcn_mfma_f32_16x16x32_bf16(av[tap][ics][0], b1, acc[0][1], 0, 0, 0);
                    acc[1][1] = __builtin_amdgcn_mfma_f32_16x16x32_bf16(av[tap][ics][1], b1, acc[1][1], 0, 0, 0);
                }
            }
        }

        // ---- epilogue: acc -> C-LDS [128 px][80 oc-pad] -> global, + stats partials
        __syncthreads();
        unsigned short* C = Xs;
#pragma unroll
        for (int sub = 0; sub < 2; ++sub)
#pragma unroll
            for (int ps = 0; ps < 2; ++ps) {
                int px  = wp + ps * 16 + l15;
                int ocb = ocw * 32 + sub * 16 + kg * 4;
                v4f a = acc[sub][ps];
                v4u pk;
#pragma unroll
                for (int r = 0; r < 4; ++r) pk[r] = f2bfbits(a[r]);
                *(v4u*)(C + px * 80 + ocb) = pk;
            }
        __syncthreads();
#pragma unroll
        for (int it = 0; it < 2; ++it) {
            int ch = it * 512 + tid;
            int pixl = ch >> 3, occ = ch & 7;
            v8s v = *(const v8s*)(C + pixl * 80 + occ * 8);
#pragma unroll
            for (int j = 0; j < 8; ++j) {
                float f = bfbits2f((unsigned short)v[j]);
                s8[j] += f; q8[j] = fmaf(f, f, q8[j]);
            }
            size_t gaddr = (pixbase + pixl) * OC_T + ocg * 64 + occ * 8;
            *(v8s*)(outp + gaddr) = v;
        }
    }

    // ---- fused stats: wave shfl-reduce (stride 8) -> LDS -> 128 atomics/block
    __syncthreads();
#pragma unroll
    for (int j = 0; j < 8; ++j) {
        float s = s8[j], q = q8[j];
        s += __shfl_down(s, 32); q += __shfl_down(q, 32);
        s += __shfl_down(s, 16); q += __shfl_down(q, 16);
        s += __shfl_down(s, 8);  q += __shfl_down(q, 8);
        s8[j] = s; q8[j] = q;
    }
    float* red = (float*)Xs;
    if (lane < 8) {
#pragma unroll
        for (int j = 0; j < 8; ++j) {
            red[(wv * 8 + lane) * 16 + j]     = s8[j];
            red[(wv * 8 + lane) * 16 + 8 + j] = q8[j];
        }
    }
    __syncthreads();
    if (tid < 64) {
        int o = tid >> 3, j = tid & 7;
        float S = 0.f, Q = 0.f;
#pragma unroll
        for (int w2 = 0; w2 < 8; ++w2) {
            S += red[(w2 * 8 + o) * 16 + j];
            Q += red[(w2 * 8 + o) * 16 + 8 + j];
        }
        int oc = ocg * 64 + o * 8 + j;
        atomicAdd(&g_stats[SOFF + 2 * oc],     S);
        atomicAdd(&g_stats[SOFF + 2 * oc + 1], Q);
    }
}

// ---------------------------------------------------------------------------
// BN + mish over NHWC bf16, 8 elems/thread (for bn1)
// ---------------------------------------------------------------------------
template<int C, int OFF>
__global__ __launch_bounds__(256) void bnN(const unsigned short* __restrict__ in,
                                           unsigned short* __restrict__ outp,
                                           const float* __restrict__ gam,
                                           const float* __restrict__ bet, int total8)
{
    const int t0 = blockIdx.x * 256 + threadIdx.x;
    const int c0 = (t0 * 8) & (C - 1);
    float sc[8], sh[8];
#pragma unroll
    for (int j = 0; j < 8; ++j) {
        int c = c0 + j;
        float m  = g_stats[OFF + 2 * c] * INV_CNT;
        float va = fmaf(g_stats[OFF + 2 * c + 1], INV_CNT, -m * m);
        sc[j] = rsqrtf(va + EPS_) * gam[c];
        sh[j] = fmaf(-m, sc[j], bet[c]);
    }
    const int stride = gridDim.x * 256;
    for (int i = t0; i < total8; i += stride) {
        v8s v = *(const v8s*)(in + (size_t)i * 8);
        v8s o;
#pragma unroll
        for (int j = 0; j < 8; ++j)
            o[j] = (short)f2bfbits(mishf(fmaf(bfbits2f((unsigned short)v[j]), sc[j], sh[j])));
        *(v8s*)(outp + (size_t)i * 8) = o;
    }
}

// ---------------------------------------------------------------------------
// haarFused: bn2+mish (+f32 residual) -> Haar -> cA out + MFMA 1x1 (192->64)
// -> raw convh (NCHW f32) + fused statsH.
// Block: 512 thr, one lowres row (128 px). Grid 1024 = 8 n x 128 rows.
// ---------------------------------------------------------------------------
__global__ __launch_bounds__(512) void haarFused(const unsigned short* __restrict__ c2,
                                                 const float* __restrict__ x,
                                                 const float* __restrict__ g2,
                                                 const float* __restrict__ be2,
                                                 float* __restrict__ out_low,
                                                 float* __restrict__ convh)
{
    __shared__ __align__(16) unsigned short Bs[128 * 192];   // 49152 B; Cf overlays
    const int tid = threadIdx.x, lane = tid & 63;
    const int n = blockIdx.x >> 7, row = blockIdx.x & 127;

    // A-fragments (whT) issued early
    const int wv = tid >> 6;
    const int ocw = wv >> 2, wp = (wv & 3) * 32;
    const int l15 = lane & 15, kg = lane >> 4;
    v8s av2[6][2];
    {
        const unsigned short* wb = g_whT + (size_t)(ocw * 32 + l15) * 192 + kg * 8;
#pragma unroll
        for (int s = 0; s < 6; ++s)
#pragma unroll
            for (int sub = 0; sub < 2; ++sub)
                av2[s][sub] = *(const v8s*)(wb + (size_t)sub * 16 * 192 + s * 32);
    }

    // ---- phase A: y = mish(bn2(c2)) + x ; Haar -> cA global + cH/cV/cD -> Bs
    {
        const int px = tid >> 2, cg = tid & 3;
        float sc[16], sh[16];
#pragma unroll
        for (int j = 0; j < 16; ++j) {
            int c = cg * 16 + j;
            float m  = g_stats[256 + 2 * c] * INV_CNT;
            float va = fmaf(g_stats[256 + 2 * c + 1], INV_CNT, -m * m);
            sc[j] = rsqrtf(va + EPS_) * g2[c];
            sh[j] = fmaf(-m, sc[j], be2[c]);
        }
        const size_t pa = ((size_t)n << 16) + ((size_t)(2 * row) << 8) + 2 * px;
        const unsigned short* cb = c2 + pa * 64 + cg * 16;
        v8s ca0 = *(const v8s*)cb,            ca1 = *(const v8s*)(cb + 8);
        v8s cb0 = *(const v8s*)(cb + 64),     cb1 = *(const v8s*)(cb + 72);
        v8s cc0 = *(const v8s*)(cb + 16384),  cc1 = *(const v8s*)(cb + 16392);
        v8s cd0 = *(const v8s*)(cb + 16448),  cd1 = *(const v8s*)(cb + 16456);
        const float* xb = x + ((size_t)n << 22) + ((size_t)(2 * row) << 8) + 2 * px;
        v8s Hh0, Hh1, Vv0, Vv1, Dd0, Dd1;
#pragma unroll
        for (int j = 0; j < 16; ++j) {
            int c = cg * 16 + j;
            const float* xc = xb + ((size_t)c << 16);
            float2 xt = *(const float2*)xc;
            float2 xu = *(const float2*)(xc + 256);
            float ya = mishf(fmaf(bfbits2f((unsigned short)(j < 8 ? ca0[j] : ca1[j - 8])), sc[j], sh[j])) + xt.x;
            float yb = mishf(fmaf(bfbits2f((unsigned short)(j < 8 ? cb0[j] : cb1[j - 8])), sc[j], sh[j])) + xt.y;
            float yc = mishf(fmaf(bfbits2f((unsigned short)(j < 8 ? cc0[j] : cc1[j - 8])), sc[j], sh[j])) + xu.x;
            float yd = mishf(fmaf(bfbits2f((unsigned short)(j < 8 ? cd0[j] : cd1[j - 8])), sc[j], sh[j])) + xu.y;
            out_low[((size_t)(n * 64 + c) << 14) + row * 128 + px] = 0.5f * (ya + yb + yc + yd);
            unsigned short hb = f2bfbits(0.5f * (ya + yb - yc - yd));
            unsigned short vb = f2bfbits(0.5f * (ya - yb + yc - yd));
            unsigned short db = f2bfbits(0.5f * (ya - yb - yc + yd));
            if (j < 8) { Hh0[j] = (short)hb; Vv0[j] = (short)vb; Dd0[j] = (short)db; }
            else       { Hh1[j-8] = (short)hb; Vv1[j-8] = (short)vb; Dd1[j-8] = (short)db; }
        }
        unsigned short* bp = Bs + px * 192;
        const int sx = px & 7;
        *(v8s*)(bp + (((cg * 2 + 0) ^ sx) << 3))       = Hh0;
        *(v8s*)(bp + (((cg * 2 + 1) ^ sx) << 3))       = Hh1;
        *(v8s*)(bp + (((8 + cg * 2 + 0) ^ sx) << 3))   = Vv0;
        *(v8s*)(bp + (((8 + cg * 2 + 1) ^ sx) << 3))   = Vv1;
        *(v8s*)(bp + (((16 + cg * 2 + 0) ^ sx) << 3))  = Dd0;
        *(v8s*)(bp + (((16 + cg * 2 + 1) ^ sx) << 3))  = Dd1;
    }
    __syncthreads();

    // ---- phase B: MFMA, K=192 (6 steps)
    v4f acc[2][2];
    {
        v4f z = {0.f, 0.f, 0.f, 0.f};
        acc[0][0] = z; acc[0][1] = z; acc[1][0] = z; acc[1][1] = z;
    }
    {
        const int pix0 = wp + l15;
        const unsigned short* bbase = Bs + pix0 * 192;
        const int sx0 = pix0 & 7;
#pragma unroll
        for (int s = 0; s < 6; ++s) {
            const int ck = s * 4 + kg;
            v8s b0 = *(const v8s*)(bbase + ((ck ^ sx0) << 3));
            v8s b1 = *(const v8s*)(bbase + 16 * 192 + ((ck ^ sx0) << 3));
            acc[0][0] = __builtin_amdgcn_mfma_f32_16x16x32_bf16(av2[s][0], b0, acc[0][0], 0, 0, 0);
            acc[1][0] = __builtin_amdgcn_mfma_f32_16x16x32_bf16(av2[s][1], b0, acc[1][0], 0, 0, 0);
            acc[0][1] = __builtin_amdgcn_mfma_f32_16x16x32_bf16(av2[s][0], b1, acc[0][1], 0, 0, 0);
            acc[1][1] = __builtin_amdgcn_mfma_f32_16x16x32_bf16(av2[s][1], b1, acc[1][1], 0, 0, 0);
        }
    }

    // ---- phase C: Cf [64 oc][130 px] f32 (overlay Bs) -> coalesced NCHW + stats
    __syncthreads();
    float* Cf = (float*)Bs;
#pragma unroll
    for (int sub = 0; sub < 2; ++sub)
#pragma unroll
        for (int ps = 0; ps < 2; ++ps) {
            const int pxe = wp + ps * 16 + l15;
            const int ocb = ocw * 32 + sub * 16 + kg * 4;
#pragma unroll
            for (int r = 0; r < 4; ++r)
                Cf[(ocb + r) * 130 + pxe] = acc[sub][ps][r];
        }
    __syncthreads();
    {
        const int oc = tid >> 3, seg = tid & 7;
        float vals[16];
        float S = 0.f, Q = 0.f;
#pragma unroll
        for (int i = 0; i < 16; ++i) {
            float f = Cf[oc * 130 + seg * 16 + i];
            vals[i] = f; S += f; Q = fmaf(f, f, Q);
        }
        float* gp = convh + ((size_t)(n * 64 + oc) << 14) + row * 128 + seg * 16;
#pragma unroll
        for (int i4 = 0; i4 < 4; ++i4) {
            float4 t4;
            t4.x = vals[i4*4]; t4.y = vals[i4*4+1]; t4.z = vals[i4*4+2]; t4.w = vals[i4*4+3];
            *(float4*)(gp + i4 * 4) = t4;
        }
        S += __shfl_down(S, 4); Q += __shfl_down(Q, 4);
        S += __shfl_down(S, 2); Q += __shfl_down(Q, 2);
        S += __shfl_down(S, 1); Q += __shfl_down(Q, 1);
        if (seg == 0) {
            atomicAdd(&g_stats[384 + 2 * oc],     S);
            atomicAdd(&g_stats[384 + 2 * oc + 1], Q);
        }
    }
}

// ---------------------------------------------------------------------------
// final BN+mish on convh (NCHW f32), in place
// ---------------------------------------------------------------------------
__global__ __launch_bounds__(256) void bnF(const float* __restrict__ in,
                                           float* __restrict__ outp, int stOff,
                                           const float* __restrict__ gam,
                                           const float* __restrict__ bet,
                                           int Cmask, int logHW, float invCnt, int total4)
{
    int t = blockIdx.x * 256 + threadIdx.x;
    if (t >= total4) return;
    int idx = t << 2;
    int c = (idx >> logHW) & Cmask;
    float mean = g_stats[stOff + 2 * c] * invCnt;
    float var = fmaf(g_stats[stOff + 2 * c + 1], invCnt, -mean * mean);
    float scale = rsqrtf(var + EPS_) * gam[c];
    float shift = fmaf(-mean, scale, bet[c]);
    float4 v = *(const float4*)(in + idx);
    v.x = mishf(fmaf(v.x, scale, shift));
    v.y = mishf(fmaf(v.y, scale, shift));
    v.z = mishf(fmaf(v.z, scale, shift));
    v.w = mishf(fmaf(v.w, scale, shift));
    *(float4*)(outp + idx) = v;
}

// ---------------------------------------------------------------------------
extern "C" void kernel_launch(void* const* d_in, const int* in_sizes, int n_in,
                              void* d_out, int out_size, void* d_ws, size_t ws_size,
                              hipStream_t stream)
{
    (void)in_sizes; (void)n_in; (void)out_size; (void)ws_size;

    const float* x   = (const float*)d_in[0];
    const float* w1  = (const float*)d_in[1];
    const float* g1  = (const float*)d_in[3];
    const float* be1 = (const float*)d_in[4];
    const float* w2  = (const float*)d_in[5];
    const float* g2  = (const float*)d_in[7];
    const float* be2 = (const float*)d_in[8];
    const float* wh  = (const float*)d_in[9];
    const float* gh  = (const float*)d_in[11];
    const float* beh = (const float*)d_in[12];
    // biases b1,b2,bh are mathematically absorbed by the following BatchNorms.

    char* ws = (char*)d_ws;
    unsigned short* xh = (unsigned short*)ws;                 // x NHWC bf16 [524288][64]
    unsigned short* h1 = (unsigned short*)(ws + 67108864);    // conv1 out NHWC bf16 [524288][128]
    unsigned short* c2 = (unsigned short*)ws;                 // conv2 raw NHWC bf16 (xh dead)
    float* out_low = (float*)d_out;
    float* convh   = (float*)d_out + 8388608;

    prep<<<288, 256, 0, stream>>>(w1, w2, wh);
    transpose_x<<<8192, 256, 0, stream>>>(x, xh);

    // conv1 (+stats1 fused): xh -> h1 raw
    convMFMA<64, 128, 0, 0><<<1024, 512, 0, stream>>>(xh, h1, 8);
    // bn1 + mish in place
    bnN<128, 0><<<1024, 256, 0, stream>>>(h1, h1, g1, be1, 8388608);
    // conv2 single-pass over both ic halves (+stats2 fused): h1 -> c2 raw (xh region)
    convMFMA<128, 64, 1, 256><<<1024, 512, 0, stream>>>(h1, c2, 4);
    // bn2+mish+residual(x f32) + haar + 1x1 MFMA (+statsH fused)
    haarFused<<<1024, 512, 0, stream>>>(c2, x, g2, be2, out_low, convh);
    // final bn+mish on convh
    bnF<<<8192, 256, 0, stream>>>(convh, convh, 384, gh, beh, 63, 14, 1.f / 131072.f, 2097152);
}

// Round 4
// 787.865 us; speedup vs baseline: 1.1790x; 1.1790x over previous
//
#include <hip/hip_runtime.h>
#include <hip/hip_bf16.h>

#define DEV static __device__ __forceinline__

typedef short v8s __attribute__((ext_vector_type(8)));
typedef float v4f __attribute__((ext_vector_type(4)));
typedef unsigned short v4u __attribute__((ext_vector_type(4)));

constexpr int N_ = 8;
constexpr float EPS_ = 1e-5f;
constexpr float INV_CNT = 1.f / 524288.f;   // 1/(8*256*256)

// device-global scratch
__device__ __align__(16) unsigned short g_wT1[9*128*64];   // [tap][oc][ic] bf16
__device__ __align__(16) unsigned short g_wT2[9*64*128];
__device__ __align__(16) unsigned short g_whT[64*192];     // [oc][k] bf16
__device__ __align__(16) float g_stats[512];               // s1[0:256) s2[256:384) sH[384:512)
__device__ __align__(16) unsigned short g_zero[64];

DEV float bfbits2f(unsigned short u) { return __uint_as_float(((unsigned)u) << 16); }
DEV unsigned short f2bfbits(float f) {
    __hip_bfloat16 h = __float2bfloat16(f);
    unsigned short b;
    __builtin_memcpy(&b, &h, 2);
    return b;
}

DEV float mishf(float v) {
    // mish(v) = v * t(t+2)/(t(t+2)+2), t = e^v
    float t = __expf(fminf(v, 30.f));
    float num = fmaf(t, t, 2.f * t);
    return v * num * __builtin_amdgcn_rcpf(num + 2.f);
}

DEV void gll16(const unsigned short* g, unsigned short* l) {
    __builtin_amdgcn_global_load_lds(
        (const __attribute__((address_space(1))) unsigned int*)g,
        (__attribute__((address_space(3))) unsigned int*)l,
        16, 0, 0);
}

// ---------------------------------------------------------------------------
// prep: weight reorders (bf16) + zero stats + zero page
// ---------------------------------------------------------------------------
__global__ __launch_bounds__(256) void prep(const float* __restrict__ w1,
                                            const float* __restrict__ w2,
                                            const float* __restrict__ wh)
{
    int idx = blockIdx.x * 256 + threadIdx.x;
    if (idx < 512) g_stats[idx] = 0.f;
    if (idx < 64) g_zero[idx] = 0;
    if (idx < 12288) g_whT[idx] = f2bfbits(wh[idx]);       // [oc][192] == OIHW flat
    if (idx < 73728) {
        int tap = idx / 8192, rem = idx & 8191;
        {   int oc = rem >> 6, ic = rem & 63;
            g_wT1[idx] = f2bfbits(w1[(oc * 64 + ic) * 9 + tap]); }
        {   int oc = rem >> 7, ic = rem & 127;
            g_wT2[idx] = f2bfbits(w2[(oc * 128 + ic) * 9 + tap]); }
    }
}

// ---------------------------------------------------------------------------
// transpose x: NCHW f32 -> NHWC bf16
// ---------------------------------------------------------------------------
__global__ __launch_bounds__(256) void transpose_x(const float* __restrict__ x,
                                                   unsigned short* __restrict__ xh)
{
    __shared__ float t[64][65];
    const int tid = threadIdx.x;
    const int bid = blockIdx.x;
    const int n = bid >> 10, pb = bid & 1023;
    const size_t pix0 = (size_t)pb * 64;
    const float* xb = x + ((size_t)n << 22) + pix0;
#pragma unroll
    for (int cb = 0; cb < 4; ++cb) {
        int c = (tid >> 4) + cb * 16;
        int p = (tid & 15) * 4;
        float4 v = *(const float4*)(xb + ((size_t)c << 16) + p);
        t[c][p] = v.x; t[c][p+1] = v.y; t[c][p+2] = v.z; t[c][p+3] = v.w;
    }
    __syncthreads();
    unsigned short* ob = xh + (((size_t)n << 16) + pix0) * 64;
#pragma unroll
    for (int pb2 = 0; pb2 < 2; ++pb2) {
        int p = (tid >> 3) + pb2 * 32;
        int c0 = (tid & 7) * 8;
        v8s r;
#pragma unroll
        for (int i = 0; i < 8; ++i) r[i] = (short)f2bfbits(t[c0 + i][p]);
        *(v8s*)(ob + (size_t)p * 64 + c0) = r;
    }
}

// ---------------------------------------------------------------------------
// MFMA implicit-GEMM 3x3 conv, pad=1, NHWC bf16.  (R2-proven structure:
// weights resident once, NO cross-loop extra state — av[9][2][2]=144 VGPR
// sits at the allocator edge; adding live regs spills it to scratch.)
// Block: 512 thr = 8 waves; block tile 64 oc x 128 pix; wave tile 32 oc x 32 pix.
// ---------------------------------------------------------------------------
template<int IC_T, int OC_T, bool ACCUM, int WSEL>
__global__ __launch_bounds__(512, 2) void convMFMA(const unsigned short* __restrict__ in,
                                                   unsigned short* __restrict__ outp,
                                                   const int icoff, const int nTiles)
{
    __shared__ __align__(16) unsigned short Xs[3 * 130 * 64];   // 49920 B; also C-tile
    const unsigned short* wT = (WSEL == 0) ? g_wT1 : g_wT2;

    const int tid  = threadIdx.x;
    const int lane = tid & 63;
    const int wv   = tid >> 6;            // 0..7
    constexpr int NOCB = OC_T / 64;
    const int ocg = (NOCB == 2) ? ((int)blockIdx.x & 1) : 0;
    const int pg  = (NOCB == 2) ? ((int)blockIdx.x >> 1) : (int)blockIdx.x;
    const int NPG = (int)gridDim.x / NOCB;

    const int ocw = wv >> 2;              // oc 32-half within block's 64
    const int wp  = (wv & 3) * 32;        // wave pixel offset
    const int l15 = lane & 15, kg = lane >> 4;

    // ---- weights -> VGPRs once: av[tap][ics][sub], A row = l15, k = kg*8..+7
    v8s av[9][2][2];
    {
        const unsigned short* wb =
            wT + ((size_t)(ocg * 64 + ocw * 32 + l15)) * IC_T + icoff + kg * 8;
#pragma unroll
        for (int tap = 0; tap < 9; ++tap)
#pragma unroll
            for (int ics = 0; ics < 2; ++ics)
#pragma unroll
                for (int sub = 0; sub < 2; ++sub)
                    av[tap][ics][sub] =
                        *(const v8s*)(wb + ((size_t)tap * OC_T + sub * 16) * IC_T + ics * 32);
    }

    for (int t = 0; t < nTiles; ++t) {
        const int pt   = pg + NPG * t;                 // 0..4095
        const int n    = pt >> 9;
        const int hrow = (pt >> 1) & 255;
        const int wblk = pt & 1;
        const int w0   = wblk * 128;
        const size_t pixbase = ((size_t)n << 16) + ((size_t)hrow << 8) + w0;

        __syncthreads();   // protect Xs from previous tile's epilogue reads

        // ---- stage X: 3120 chunks of 16B
        {
            const int cb0 = wv * 64;
#pragma unroll
            for (int it = 0; it < 7; ++it) {
                int cb = it * 512 + cb0;               // wave-uniform chunk base
                int chunk = cb + lane;
                if (chunk < 3120) {
                    int r   = chunk / 1040;
                    int rem = chunk - r * 1040;
                    int lc  = rem >> 3, k = rem & 7;
                    int gr  = hrow - 1 + r;
                    int gc  = w0 - 1 + lc;
                    const unsigned short* src;
                    if (((unsigned)gr < 256u) & ((unsigned)gc < 256u))
                        src = in + ((((size_t)n << 16) + ((size_t)gr << 8) + gc) * IC_T)
                                 + icoff + ((k ^ (lc & 7)) << 3);
                    else
                        src = g_zero;
                    gll16(src, Xs + (size_t)cb * 8);
                }
            }
        }
        __syncthreads();   // drains vmcnt

        // ---- MFMA k-loop: 9 taps x 2 ic-subgroups
        v4f acc[2][2];
        {
            v4f z = {0.f, 0.f, 0.f, 0.f};
            acc[0][0] = z; acc[0][1] = z; acc[1][0] = z; acc[1][1] = z;
        }
#pragma unroll
        for (int tap = 0; tap < 9; ++tap) {
            const int dyy = tap / 3, dxx = tap % 3;
            const int lc0 = wp + l15 + dxx;
#pragma unroll
            for (int ics = 0; ics < 2; ++ics) {
                const int off0 = ((dyy * 130 + lc0) * 8 + ((ics * 4 + kg) ^ (lc0 & 7))) * 8;
                v8s b0 = *(const v8s*)(Xs + off0);
                v8s b1 = *(const v8s*)(Xs + off0 + 16 * 64);   // lc0+16: same (lc&7)
                acc[0][0] = __builtin_amdgcn_mfma_f32_16x16x32_bf16(av[tap][ics][0], b0, acc[0][0], 0, 0, 0);
                acc[1][0] = __builtin_amdgcn_mfma_f32_16x16x32_bf16(av[tap][ics][1], b0, acc[1][0], 0, 0, 0);
                acc[0][1] = __builtin_amdgcn_mfma_f32_16x16x32_bf16(av[tap][ics][0], b1, acc[0][1], 0, 0, 0);
                acc[1][1] = __builtin_amdgcn_mfma_f32_16x16x32_bf16(av[tap][ics][1], b1, acc[1][1], 0, 0, 0);
            }
        }

        // ---- epilogue: acc -> CLDS [128 pix][80 oc-pad] -> global (coalesced)
        __syncthreads();
        unsigned short* C = Xs;
#pragma unroll
        for (int sub = 0; sub < 2; ++sub)
#pragma unroll
            for (int ps = 0; ps < 2; ++ps) {
                int px  = wp + ps * 16 + l15;
                int ocb = ocw * 32 + sub * 16 + kg * 4;
                v4f a = acc[sub][ps];
                v4u pk;
#pragma unroll
                for (int r = 0; r < 4; ++r) pk[r] = f2bfbits(a[r]);
                *(v4u*)(C + px * 80 + ocb) = pk;
            }
        __syncthreads();
#pragma unroll
        for (int it = 0; it < 2; ++it) {
            int ch = it * 512 + tid;                    // 0..1023
            int pixl = ch >> 3, occ = ch & 7;
            v8s v = *(const v8s*)(C + pixl * 80 + occ * 8);
            size_t gaddr = (pixbase + pixl) * OC_T + ocg * 64 + occ * 8;
            if (ACCUM) {
                v8s pv = *(const v8s*)(outp + gaddr);
#pragma unroll
                for (int j = 0; j < 8; ++j)
                    v[j] = (short)f2bfbits(bfbits2f((unsigned short)v[j]) +
                                           bfbits2f((unsigned short)pv[j]));
            }
            *(v8s*)(outp + gaddr) = v;
        }
    }
}

// ---------------------------------------------------------------------------
// per-channel stats over NHWC bf16 [P][C]
// ---------------------------------------------------------------------------
template<int C, int OFF>
__global__ __launch_bounds__(256) void statsN(const unsigned short* __restrict__ in, int P)
{
    constexpr int G = C / 8;
    constexpr int LG = (G == 16) ? 4 : 3;
    __shared__ float red[256 * 8];
    const int tid = threadIdx.x;
    const int cg = tid & (G - 1);
    float s[8], q[8];
#pragma unroll
    for (int j = 0; j < 8; ++j) { s[j] = 0.f; q[j] = 0.f; }
    const int tot = P * G;
    const int stride = gridDim.x * 256;
    for (int i = blockIdx.x * 256 + tid; i < tot; i += stride) {
        const int p = i >> LG;
        v8s v = *(const v8s*)(in + (size_t)p * C + cg * 8);
#pragma unroll
        for (int j = 0; j < 8; ++j) {
            float f = bfbits2f((unsigned short)v[j]);
            s[j] += f; q[j] = fmaf(f, f, q[j]);
        }
    }
#pragma unroll
    for (int j = 0; j < 8; ++j) red[tid * 8 + j] = s[j];
    __syncthreads();
    for (int st = (256 / G) >> 1; st > 0; st >>= 1) {
        if ((tid >> LG) < st)
#pragma unroll
            for (int j = 0; j < 8; ++j) red[tid * 8 + j] += red[(tid + st * G) * 8 + j];
        __syncthreads();
    }
    if (tid < G)
#pragma unroll
        for (int j = 0; j < 8; ++j) atomicAdd(&g_stats[OFF + 2 * (cg * 8 + j)], red[tid * 8 + j]);
    __syncthreads();
#pragma unroll
    for (int j = 0; j < 8; ++j) red[tid * 8 + j] = q[j];
    __syncthreads();
    for (int st = (256 / G) >> 1; st > 0; st >>= 1) {
        if ((tid >> LG) < st)
#pragma unroll
            for (int j = 0; j < 8; ++j) red[tid * 8 + j] += red[(tid + st * G) * 8 + j];
        __syncthreads();
    }
    if (tid < G)
#pragma unroll
        for (int j = 0; j < 8; ++j) atomicAdd(&g_stats[OFF + 2 * (cg * 8 + j) + 1], red[tid * 8 + j]);
}

// ---------------------------------------------------------------------------
// BN + mish over NHWC bf16, 8 elems/thread (bn1)
// ---------------------------------------------------------------------------
template<int C, int OFF>
__global__ __launch_bounds__(256) void bnN(const unsigned short* __restrict__ in,
                                           unsigned short* __restrict__ outp,
                                           const float* __restrict__ gam,
                                           const float* __restrict__ bet, int total8)
{
    const int t0 = blockIdx.x * 256 + threadIdx.x;
    const int c0 = (t0 * 8) & (C - 1);
    float sc[8], sh[8];
#pragma unroll
    for (int j = 0; j < 8; ++j) {
        int c = c0 + j;
        float m  = g_stats[OFF + 2 * c] * INV_CNT;
        float va = fmaf(g_stats[OFF + 2 * c + 1], INV_CNT, -m * m);
        sc[j] = rsqrtf(va + EPS_) * gam[c];
        sh[j] = fmaf(-m, sc[j], bet[c]);
    }
    const int stride = gridDim.x * 256;
    for (int i = t0; i < total8; i += stride) {
        v8s v = *(const v8s*)(in + (size_t)i * 8);
        v8s o;
#pragma unroll
        for (int j = 0; j < 8; ++j)
            o[j] = (short)f2bfbits(mishf(fmaf(bfbits2f((unsigned short)v[j]), sc[j], sh[j])));
        *(v8s*)(outp + (size_t)i * 8) = o;
    }
}

// ---------------------------------------------------------------------------
// haarFused: bn2+mish (+f32 residual) -> Haar -> cA out + MFMA 1x1 (192->64)
// -> raw convh (NCHW f32) + fused statsH.
// Block: 512 thr, one lowres row (128 px). Grid 1024 = 8 n x 128 rows.
// ---------------------------------------------------------------------------
__global__ __launch_bounds__(512) void haarFused(const unsigned short* __restrict__ c2,
                                                 const float* __restrict__ x,
                                                 const float* __restrict__ g2,
                                                 const float* __restrict__ be2,
                                                 float* __restrict__ out_low,
                                                 float* __restrict__ convh)
{
    __shared__ __align__(16) unsigned short Bs[128 * 192];   // 49152 B; Cf overlays
    const int tid = threadIdx.x, lane = tid & 63;
    const int n = blockIdx.x >> 7, row = blockIdx.x & 127;

    const int wv = tid >> 6;
    const int ocw = wv >> 2, wp = (wv & 3) * 32;
    const int l15 = lane & 15, kg = lane >> 4;
    v8s av2[6][2];
    {
        const unsigned short* wb = g_whT + (size_t)(ocw * 32 + l15) * 192 + kg * 8;
#pragma unroll
        for (int s = 0; s < 6; ++s)
#pragma unroll
            for (int sub = 0; sub < 2; ++sub)
                av2[s][sub] = *(const v8s*)(wb + (size_t)sub * 16 * 192 + s * 32);
    }

    // ---- phase A: y = mish(bn2(c2)) + x ; Haar -> cA global + cH/cV/cD -> Bs
    {
        const int px = tid >> 2, cg = tid & 3;
        float sc[16], sh[16];
#pragma unroll
        for (int j = 0; j < 16; ++j) {
            int c = cg * 16 + j;
            float m  = g_stats[256 + 2 * c] * INV_CNT;
            float va = fmaf(g_stats[256 + 2 * c + 1], INV_CNT, -m * m);
            sc[j] = rsqrtf(va + EPS_) * g2[c];
            sh[j] = fmaf(-m, sc[j], be2[c]);
        }
        const size_t pa = ((size_t)n << 16) + ((size_t)(2 * row) << 8) + 2 * px;
        const unsigned short* cb = c2 + pa * 64 + cg * 16;
        v8s ca0 = *(const v8s*)cb,            ca1 = *(const v8s*)(cb + 8);
        v8s cb0 = *(const v8s*)(cb + 64),     cb1 = *(const v8s*)(cb + 72);
        v8s cc0 = *(const v8s*)(cb + 16384),  cc1 = *(const v8s*)(cb + 16392);
        v8s cd0 = *(const v8s*)(cb + 16448),  cd1 = *(const v8s*)(cb + 16456);
        const float* xb = x + ((size_t)n << 22) + ((size_t)(2 * row) << 8) + 2 * px;
        v8s Hh0, Hh1, Vv0, Vv1, Dd0, Dd1;
#pragma unroll
        for (int j = 0; j < 16; ++j) {
            int c = cg * 16 + j;
            const float* xc = xb + ((size_t)c << 16);
            float2 xt = *(const float2*)xc;
            float2 xu = *(const float2*)(xc + 256);
            float ya = mishf(fmaf(bfbits2f((unsigned short)(j < 8 ? ca0[j] : ca1[j - 8])), sc[j], sh[j])) + xt.x;
            float yb = mishf(fmaf(bfbits2f((unsigned short)(j < 8 ? cb0[j] : cb1[j - 8])), sc[j], sh[j])) + xt.y;
            float yc = mishf(fmaf(bfbits2f((unsigned short)(j < 8 ? cc0[j] : cc1[j - 8])), sc[j], sh[j])) + xu.x;
            float yd = mishf(fmaf(bfbits2f((unsigned short)(j < 8 ? cd0[j] : cd1[j - 8])), sc[j], sh[j])) + xu.y;
            out_low[((size_t)(n * 64 + c) << 14) + row * 128 + px] = 0.5f * (ya + yb + yc + yd);
            unsigned short hb = f2bfbits(0.5f * (ya + yb - yc - yd));
            unsigned short vb = f2bfbits(0.5f * (ya - yb + yc - yd));
            unsigned short db = f2bfbits(0.5f * (ya - yb - yc + yd));
            if (j < 8) { Hh0[j] = (short)hb; Vv0[j] = (short)vb; Dd0[j] = (short)db; }
            else       { Hh1[j-8] = (short)hb; Vv1[j-8] = (short)vb; Dd1[j-8] = (short)db; }
        }
        unsigned short* bp = Bs + px * 192;
        const int sx = px & 7;
        *(v8s*)(bp + (((cg * 2 + 0) ^ sx) << 3))       = Hh0;
        *(v8s*)(bp + (((cg * 2 + 1) ^ sx) << 3))       = Hh1;
        *(v8s*)(bp + (((8 + cg * 2 + 0) ^ sx) << 3))   = Vv0;
        *(v8s*)(bp + (((8 + cg * 2 + 1) ^ sx) << 3))   = Vv1;
        *(v8s*)(bp + (((16 + cg * 2 + 0) ^ sx) << 3))  = Dd0;
        *(v8s*)(bp + (((16 + cg * 2 + 1) ^ sx) << 3))  = Dd1;
    }
    __syncthreads();

    // ---- phase B: MFMA, K=192 (6 steps)
    v4f acc[2][2];
    {
        v4f z = {0.f, 0.f, 0.f, 0.f};
        acc[0][0] = z; acc[0][1] = z; acc[1][0] = z; acc[1][1] = z;
    }
    {
        const int pix0 = wp + l15;
        const unsigned short* bbase = Bs + pix0 * 192;
        const int sx0 = pix0 & 7;
#pragma unroll
        for (int s = 0; s < 6; ++s) {
            const int ck = s * 4 + kg;
            v8s b0 = *(const v8s*)(bbase + ((ck ^ sx0) << 3));
            v8s b1 = *(const v8s*)(bbase + 16 * 192 + ((ck ^ sx0) << 3));
            acc[0][0] = __builtin_amdgcn_mfma_f32_16x16x32_bf16(av2[s][0], b0, acc[0][0], 0, 0, 0);
            acc[1][0] = __builtin_amdgcn_mfma_f32_16x16x32_bf16(av2[s][1], b0, acc[1][0], 0, 0, 0);
            acc[0][1] = __builtin_amdgcn_mfma_f32_16x16x32_bf16(av2[s][0], b1, acc[0][1], 0, 0, 0);
            acc[1][1] = __builtin_amdgcn_mfma_f32_16x16x32_bf16(av2[s][1], b1, acc[1][1], 0, 0, 0);
        }
    }

    // ---- phase C: Cf [64 oc][130 px] f32 (overlay Bs) -> coalesced NCHW + stats
    __syncthreads();
    float* Cf = (float*)Bs;
#pragma unroll
    for (int sub = 0; sub < 2; ++sub)
#pragma unroll
        for (int ps = 0; ps < 2; ++ps) {
            const int pxe = wp + ps * 16 + l15;
            const int ocb = ocw * 32 + sub * 16 + kg * 4;
#pragma unroll
            for (int r = 0; r < 4; ++r)
                Cf[(ocb + r) * 130 + pxe] = acc[sub][ps][r];
        }
    __syncthreads();
    {
        const int oc = tid >> 3, seg = tid & 7;
        float vals[16];
        float S = 0.f, Q = 0.f;
#pragma unroll
        for (int i = 0; i < 16; ++i) {
            float f = Cf[oc * 130 + seg * 16 + i];
            vals[i] = f; S += f; Q = fmaf(f, f, Q);
        }
        float* gp = convh + ((size_t)(n * 64 + oc) << 14) + row * 128 + seg * 16;
#pragma unroll
        for (int i4 = 0; i4 < 4; ++i4) {
            float4 t4;
            t4.x = vals[i4*4]; t4.y = vals[i4*4+1]; t4.z = vals[i4*4+2]; t4.w = vals[i4*4+3];
            *(float4*)(gp + i4 * 4) = t4;
        }
        S += __shfl_down(S, 4); Q += __shfl_down(Q, 4);
        S += __shfl_down(S, 2); Q += __shfl_down(Q, 2);
        S += __shfl_down(S, 1); Q += __shfl_down(Q, 1);
        if (seg == 0) {
            atomicAdd(&g_stats[384 + 2 * oc],     S);
            atomicAdd(&g_stats[384 + 2 * oc + 1], Q);
        }
    }
}

// ---------------------------------------------------------------------------
// final BN+mish on convh (NCHW f32), in place
// ---------------------------------------------------------------------------
__global__ __launch_bounds__(256) void bnF(const float* __restrict__ in,
                                           float* __restrict__ outp, int stOff,
                                           const float* __restrict__ gam,
                                           const float* __restrict__ bet,
                                           int Cmask, int logHW, float invCnt, int total4)
{
    int t = blockIdx.x * 256 + threadIdx.x;
    if (t >= total4) return;
    int idx = t << 2;
    int c = (idx >> logHW) & Cmask;
    float mean = g_stats[stOff + 2 * c] * invCnt;
    float var = fmaf(g_stats[stOff + 2 * c + 1], invCnt, -mean * mean);
    float scale = rsqrtf(var + EPS_) * gam[c];
    float shift = fmaf(-mean, scale, bet[c]);
    float4 v = *(const float4*)(in + idx);
    v.x = mishf(fmaf(v.x, scale, shift));
    v.y = mishf(fmaf(v.y, scale, shift));
    v.z = mishf(fmaf(v.z, scale, shift));
    v.w = mishf(fmaf(v.w, scale, shift));
    *(float4*)(outp + idx) = v;
}

// ---------------------------------------------------------------------------
extern "C" void kernel_launch(void* const* d_in, const int* in_sizes, int n_in,
                              void* d_out, int out_size, void* d_ws, size_t ws_size,
                              hipStream_t stream)
{
    (void)in_sizes; (void)n_in; (void)out_size; (void)ws_size;

    const float* x   = (const float*)d_in[0];
    const float* w1  = (const float*)d_in[1];
    const float* g1  = (const float*)d_in[3];
    const float* be1 = (const float*)d_in[4];
    const float* w2  = (const float*)d_in[5];
    const float* g2  = (const float*)d_in[7];
    const float* be2 = (const float*)d_in[8];
    const float* wh  = (const float*)d_in[9];
    const float* gh  = (const float*)d_in[11];
    const float* beh = (const float*)d_in[12];
    // biases b1,b2,bh are mathematically absorbed by the following BatchNorms.

    char* ws = (char*)d_ws;
    unsigned short* xh = (unsigned short*)ws;                 // x NHWC bf16 [524288][64]
    unsigned short* h1 = (unsigned short*)(ws + 67108864);    // conv1 out NHWC bf16 [524288][128]
    unsigned short* c2 = (unsigned short*)ws;                 // conv2 raw NHWC bf16 (xh dead)
    float* out_low = (float*)d_out;
    float* convh   = (float*)d_out + 8388608;

    prep<<<288, 256, 0, stream>>>(w1, w2, wh);
    transpose_x<<<8192, 256, 0, stream>>>(x, xh);

    // conv1: xh -> h1 raw
    convMFMA<64, 128, false, 0><<<1024, 512, 0, stream>>>(xh, h1, 0, 8);
    statsN<128, 0><<<256, 256, 0, stream>>>(h1, 524288);
    // bn1 + mish in place
    bnN<128, 0><<<1024, 256, 0, stream>>>(h1, h1, g1, be1, 8388608);
    // conv2: two 64-ic passes (pass 2 accumulates); output to xh region
    convMFMA<128, 64, false, 1><<<1024, 512, 0, stream>>>(h1, c2, 0, 4);
    convMFMA<128, 64, true, 1><<<1024, 512, 0, stream>>>(h1, c2, 64, 4);
    statsN<64, 256><<<256, 256, 0, stream>>>(c2, 524288);
    // bn2+mish+residual(x f32) + haar + 1x1 MFMA (+statsH fused)
    haarFused<<<1024, 512, 0, stream>>>(c2, x, g2, be2, out_low, convh);
    // final bn+mish on convh
    bnF<<<8192, 256, 0, stream>>>(convh, convh, 384, gh, beh, 63, 14, 1.f / 131072.f, 2097152);
}